// Round 8
// baseline (90.688 us; speedup 1.0000x reference)
//
#include <hip/hip_runtime.h>
#include <math.h>

// x: (B,S,G,D) f32, norm_scale: (G,D) f32, conv_kernel: (K, G*D) f32
// out: (B,S,G,D) f32.  B=4, S=4096, G=4, D=1024, K=4, C=4096
constexpr int B = 4;
constexpr int S = 4096;
constexpr int G = 4;
constexpr int D = 1024;
constexpr int K = 4;
constexpr int C = G * D;
constexpr int STRIP = 32;            // s-rows per wave: 2048 waves, 8/CU
constexpr float EPS = 1e-6f;

typedef float v4f __attribute__((ext_vector_type(4)));

// Wave-autonomous fused RMSNorm + causal depthwise conv1d (K=4) + SiLU.
// One wave owns a (b,g,32-row strip); 64 lanes x 16 ch = D. RMS reduce is
// wave-internal shfl. NO barriers, NO LDS. TWO rows per iteration: the two
// 6-step shfl chains interleave (2x ILP on the serial reduce), and the
// iteration count / vmcnt checkpoints halve. 2-pair (4-row) load pipeline.
__global__ __launch_bounds__(256)
void shortconv_wave_kernel(const float* __restrict__ x,
                           const float* __restrict__ scale,
                           const float* __restrict__ w,
                           float* __restrict__ out)
{
    const int tid   = threadIdx.x;
    const int lane  = tid & 63;
    const int wid   = tid >> 6;
    const int gw    = blockIdx.x * 4 + wid;   // global wave id, 0..2047
    const int nstr  = S / STRIP;              // 128 strips per (b,g)
    const int strip = gw & (nstr - 1);
    const int bg    = gw >> 7;                // 0..15
    const int b     = bg >> 2;
    const int g     = bg & 3;
    const int s0    = strip * STRIP;
    const int send  = s0 + STRIP;

    // lane owns channels g*D + lane*4 + j*256 (each j-chunk = 1KB coalesced)
    const size_t base = (size_t)b * S * C + (size_t)g * D + (size_t)(lane * 4);
    const int    coff = g * D + lane * 4;

    // Conv taps with the RMSNorm scale folded in: wt'_k = wt_k * sc.
    v4f wt0[4], wt1[4], wt2[4], wt3[4];
    #pragma unroll
    for (int j = 0; j < 4; ++j) {
        const v4f sc = *(const v4f*)(scale + coff + j * 256);
        wt0[j] = *(const v4f*)(w + 0 * C + coff + j * 256) * sc;
        wt1[j] = *(const v4f*)(w + 1 * C + coff + j * 256) * sc;
        wt2[j] = *(const v4f*)(w + 2 * C + coff + j * 256) * sc;
        wt3[j] = *(const v4f*)(w + 3 * C + coff + j * 256) * sc;
    }

    // Window of normalized rows (x*invr): n0=s-3, n1=s-2, n2=s-1
    // (s = first row of current pair). Raw rows: cur pair (s,s+1),
    // fA pair (s+2,s+3) in flight; next pair issued in-loop.
    v4f n0[4], n1[4], n2[4];
    v4f cur0[4], cur1[4], fA0[4], fA1[4];
    #pragma unroll
    for (int j = 0; j < 4; ++j) { n0[j] = (v4f)0.f; n1[j] = (v4f)0.f; n2[j] = (v4f)0.f; }

    // Pipeline starts at s = s0-4 (pair-aligned); rows < 0 read as zero.
    {
        const int s = s0 - 4;
        #pragma unroll
        for (int j = 0; j < 4; ++j)
            cur0[j] = (s >= 0)     ? *(const v4f*)(x + base + (size_t)(s    ) * C + j * 256) : (v4f)0.f;
        #pragma unroll
        for (int j = 0; j < 4; ++j)
            cur1[j] = (s + 1 >= 0) ? *(const v4f*)(x + base + (size_t)(s + 1) * C + j * 256) : (v4f)0.f;
        #pragma unroll
        for (int j = 0; j < 4; ++j)
            fA0[j]  = (s + 2 >= 0) ? *(const v4f*)(x + base + (size_t)(s + 2) * C + j * 256) : (v4f)0.f;
        #pragma unroll
        for (int j = 0; j < 4; ++j)
            fA1[j]  = (s + 3 >= 0) ? *(const v4f*)(x + base + (size_t)(s + 3) * C + j * 256) : (v4f)0.f;
    }

    for (int s = s0 - 4; s < send; s += 2) {
        // Issue deepest prefetch pair (rows s+4, s+5; always >= s0 >= 0).
        v4f fB0[4], fB1[4];
        if (s + 4 < send) {
            #pragma unroll
            for (int j = 0; j < 4; ++j)
                fB0[j] = *(const v4f*)(x + base + (size_t)(s + 4) * C + j * 256);
            #pragma unroll
            for (int j = 0; j < 4; ++j)
                fB1[j] = *(const v4f*)(x + base + (size_t)(s + 5) * C + j * 256);
        } else {
            #pragma unroll
            for (int j = 0; j < 4; ++j) { fB0[j] = (v4f)0.f; fB1[j] = (v4f)0.f; }
        }

        // Two independent sum-of-squares reduces (interleaved shfl chains).
        v4f a0 = cur0[0] * cur0[0];
        a0 += cur0[1] * cur0[1];
        a0 += cur0[2] * cur0[2];
        a0 += cur0[3] * cur0[3];
        v4f a1 = cur1[0] * cur1[0];
        a1 += cur1[1] * cur1[1];
        a1 += cur1[2] * cur1[2];
        a1 += cur1[3] * cur1[3];
        float l0 = a0.x + a0.y + a0.z + a0.w;
        float l1 = a1.x + a1.y + a1.z + a1.w;
        #pragma unroll
        for (int off = 32; off > 0; off >>= 1) {
            l0 += __shfl_xor(l0, off, 64);
            l1 += __shfl_xor(l1, off, 64);
        }
        const float invr0 = rsqrtf(l0 * (1.0f / D) + EPS);
        const float invr1 = rsqrtf(l1 * (1.0f / D) + EPS);

        v4f n3[4], n4[4];
        #pragma unroll
        for (int j = 0; j < 4; ++j) {
            n3[j] = cur0[j] * invr0;
            n4[j] = cur1[j] * invr1;
        }

        if (s >= s0) {
            #pragma unroll
            for (int j = 0; j < 4; ++j) {
                v4f y0 = wt0[j] * n0[j] + wt1[j] * n1[j]
                       + wt2[j] * n2[j] + wt3[j] * n3[j];
                v4f y1 = wt0[j] * n1[j] + wt1[j] * n2[j]
                       + wt2[j] * n3[j] + wt3[j] * n4[j];
                y0.x *= __builtin_amdgcn_rcpf(1.f + __expf(-y0.x));
                y0.y *= __builtin_amdgcn_rcpf(1.f + __expf(-y0.y));
                y0.z *= __builtin_amdgcn_rcpf(1.f + __expf(-y0.z));
                y0.w *= __builtin_amdgcn_rcpf(1.f + __expf(-y0.w));
                y1.x *= __builtin_amdgcn_rcpf(1.f + __expf(-y1.x));
                y1.y *= __builtin_amdgcn_rcpf(1.f + __expf(-y1.y));
                y1.z *= __builtin_amdgcn_rcpf(1.f + __expf(-y1.z));
                y1.w *= __builtin_amdgcn_rcpf(1.f + __expf(-y1.w));
                __builtin_nontemporal_store(y0, (v4f*)(out + base + (size_t)(s    ) * C + j * 256));
                __builtin_nontemporal_store(y1, (v4f*)(out + base + (size_t)(s + 1) * C + j * 256));
            }
        }

        // Rotate: window shifts by 2; raw pairs advance.
        #pragma unroll
        for (int j = 0; j < 4; ++j) {
            n0[j] = n2[j];  n1[j] = n3[j];  n2[j] = n4[j];
            cur0[j] = fA0[j]; cur1[j] = fA1[j];
            fA0[j] = fB0[j];  fA1[j] = fB1[j];
        }
    }
}

extern "C" void kernel_launch(void* const* d_in, const int* in_sizes, int n_in,
                              void* d_out, int out_size, void* d_ws, size_t ws_size,
                              hipStream_t stream) {
    const float* x     = (const float*)d_in[0];
    const float* scale = (const float*)d_in[1];
    const float* w     = (const float*)d_in[2];
    float* out         = (float*)d_out;

    const int total_waves = (S / STRIP) * B * G;   // 2048
    dim3 grid(total_waves / 4);                    // 512 blocks of 4 waves
    dim3 block(256);
    shortconv_wave_kernel<<<grid, block, 0, stream>>>(x, scale, w, out);
}